// Round 15
// baseline (533.620 us; speedup 1.0000x reference)
//
#include <hip/hip_runtime.h>
#include <hip/hip_bf16.h>
#include <cstddef>
#include <cstdint>

#define NN 2048      // nodes (M and K of the big GEMMs)
#define CIN 2
#define HH 32        // hidden
#define EMB 16
#define HOR 12
#define BB 32        // batch
#define TT 16        // time steps
#define GC 128       // 4*HH gate channels
#define XCOLS 1024   // B*T*C
#define HCOLS 1024   // B*H  (GEMM N dim)

// Tiled fp16 operand layouts (32-k tiles, 8-elem chunks):
//   A2t [tt=64][ko=4][row=2048][e=8] : elem ((tt*4+ko)*2048+row)*8+e = A[row][tt*32+ko*8+e]
//   hTt [tt=64][ko=4][col=1024][e=8] : elem ((tt*4+ko)*1024+col)*8+e = h[node=tt*32+ko*8+e][col]
//   B2xt: hi plane same shape as hTt; lo plane at +LOPLANE elements.
#define ATILE_STRIDE 65536   // 4*2048*8 elements per 32-k tile of A
#define BTILE_STRIDE 32768   // 4*1024*8 elements per 32-k tile of B
#define LOPLANE 2097152      // elements per x plane (64*4*1024*8)

typedef __attribute__((ext_vector_type(8))) _Float16 f16x8;
typedef __attribute__((ext_vector_type(16))) float f32x16;

__device__ __forceinline__ void load_lds16(const void* g, void* l) {
    __builtin_amdgcn_global_load_lds(
        (const __attribute__((address_space(1))) void*)g,
        (__attribute__((address_space(3))) void*)l, 16, 0, 0);
}

// ---------------------------------------------------------------------------
// Kernel 0: E2T[k][j] = E2[j][k]  (128 KB; enables coalesced softmax loads)
// ---------------------------------------------------------------------------
__global__ __launch_bounds__(256) void e2_transpose(const float* __restrict__ E2,
                                                    float* __restrict__ E2T) {
    const int idx = blockIdx.x * 256 + threadIdx.x;   // 32768 elements
    const int k = idx >> 11;
    const int j = idx & 2047;
    E2T[idx] = E2[j * EMB + k];     // write coalesced; read strided (tiny)
}

// ---------------------------------------------------------------------------
// Kernel 1 (merged): blocks [0,512): adjacency softmax, wave-per-row with
// lane-coalesced E2T loads + shfl reductions. Blocks [512,1536): x -> B2xt
// hi/lo (one f16x8 store per plane). Block 1536: weight prep.
// ---------------------------------------------------------------------------
__global__ __launch_bounds__(256) void precompute(const float* __restrict__ E1,
                                                  const float* __restrict__ E2T,
                                                  const float* __restrict__ x,
                                                  const float* __restrict__ Wx,
                                                  const float* __restrict__ bx,
                                                  const float* __restrict__ Wh,
                                                  const float* __restrict__ bh,
                                                  _Float16* __restrict__ A2,
                                                  _Float16* __restrict__ B2x,
                                                  _Float16* __restrict__ W16,
                                                  float* __restrict__ Wxr,
                                                  float* __restrict__ bfold) {
    const int blk = blockIdx.x;
    const int tid = threadIdx.x;

    if (blk < 512) {
        // ---- adjacency softmax: row i, lane l owns j = c*64 + l
        const int i = blk * 4 + (tid >> 6);
        const int l = tid & 63;
        float e1[EMB];
#pragma unroll
        for (int k = 0; k < EMB; ++k) e1[k] = E1[i * EMB + k];   // uniform

        float s[32];
#pragma unroll
        for (int c = 0; c < 32; ++c) s[c] = 0.f;
#pragma unroll
        for (int k = 0; k < EMB; ++k) {
            const float ek = e1[k];
            const float* p = E2T + k * 2048 + l;
#pragma unroll
            for (int c = 0; c < 32; ++c) s[c] = fmaf(ek, p[c * 64], s[c]);
        }
        float mx = 0.f;                         // relu floor
#pragma unroll
        for (int c = 0; c < 32; ++c) { s[c] = fmaxf(s[c], 0.f); mx = fmaxf(mx, s[c]); }
#pragma unroll
        for (int off = 32; off > 0; off >>= 1) mx = fmaxf(mx, __shfl_xor(mx, off, 64));
        float sum = 0.f;
#pragma unroll
        for (int c = 0; c < 32; ++c) { s[c] = expf(s[c] - mx); sum += s[c]; }
#pragma unroll
        for (int off = 32; off > 0; off >>= 1) sum += __shfl_xor(sum, off, 64);
        const float inv = 1.0f / sum;
        // store: j = c*64+l -> chunk (j>>3) = c*8 + (l>>3), elem j&7 = l&7
        const int chb = (l >> 3);
        const int e   = l & 7;
#pragma unroll
        for (int c = 0; c < 32; ++c)
            A2[((size_t)(c * 8 + chb) * 2048 + i) * 8 + e] = (_Float16)(s[c] * inv);
    } else if (blk < 512 + 1024) {
        // ---- x transpose: idx -> (jc, col); thread owns 8 contiguous nodes
        const int idx = (blk - 512) * 256 + tid;
        const int col = idx & 1023;              // (b*T+t)*C + c
        const int jc  = idx >> 10;               // node chunk 0..255
        const int bt  = col >> 1;
        const int c   = col & 1;
        const float* xp = x + ((size_t)bt * NN + jc * 8) * CIN + c;
        f16x8 vh, vl;
#pragma unroll
        for (int e = 0; e < 8; ++e) {
            const float v = xp[e * CIN];
            const _Float16 hi = (_Float16)v;
            vh[e] = hi;
            vl[e] = (_Float16)(v - (float)hi);
        }
        const size_t base = ((size_t)jc * 1024 + col) * 8;
        *(f16x8*)(B2x + base) = vh;
        *(f16x8*)(B2x + base + LOPLANE) = vl;
    } else {
        // ---- weight prep (single block)
#pragma unroll
        for (int r = 0; r < 32; ++r) {
            const int idx = r * 256 + tid;      // 8192 frag entries
            const int e  = idx & 7;
            const int ln = (idx >> 3) & 63;
            const int gq = (idx >> 9) & 3;
            const int kh = (idx >> 11) & 1;
            const int k  = kh * 16 + (ln >> 5) * 8 + e;
            const int ch = gq * 32 + (ln & 31); // channel = h*4 + gate
            const float v = Wh[k * GC + (ch & 3) * HH + (ch >> 2)];
            const _Float16 hi = (_Float16)v;
            W16[idx] = hi;
            W16[8192 + idx] = (_Float16)(v - (float)hi);
        }
        {
            const int idx = tid;                // 256
            const int c = idx >> 7, rem = idx & 127;
            const int h = rem >> 2, g = rem & 3;
            Wxr[idx] = Wx[c * GC + g * HH + h];
        }
        if (tid < 128) {
            const int h = tid >> 2, g = tid & 3;
            bfold[tid] = bx[g * HH + h] + bh[g * HH + h];
        }
    }
}

// ---------------------------------------------------------------------------
// Kernel 3: fused full-K fp16 MFMA GEMM (32x32x16) + MFMA gate epilogue.
// Tile M=64 x N=128, K=2048. Grid 256, 1 block/CU.
// ROUND 15: 1024 threads = 16 waves -> 4 WAVES/SIMD (was 2). Wave (ws, kv):
// ws = w&7 gives (mi = ws>>2, gq = ws&3) output tile as before; kv = w>>3
// splits the K-work: NPROD=1: kv = which 32k-subtile of each BK=64 step;
// NPROD=2: kv = which x plane (hi/lo). Total LDS reads / DMA / MFMA counts
// are IDENTICAL to round 10 — just spread over 2x waves so each SIMD has 4
// waves to schedule around ds_read/vmcnt stalls. Partial accs (disjoint
// k-ranges) are summed once at the end via a 32KB LDS exchange placed in
// staging buffers that are provably dead by then.
// Staging: shared, groups g = w + 16*i (NG=24|20); per-wave DMA count
// L = 2|1 -> counted vmcnt literals scaled accordingly. Loop structure,
// buffers, and barriers are round 10's verbatim.
// GATE epilogue: kv0 writes ah planes; gate GEMM batches split kv0:{b0,b1}
// kv1:{b2,b3}; pointwise handles 2 batches concurrently (two gl buffers).
// ---------------------------------------------------------------------------
template <int NPROD, int GATE>
__global__ __launch_bounds__(1024, 1) void gemm_fused(const _Float16* __restrict__ A2,
                                                      const _Float16* __restrict__ B2,
                                                      float* __restrict__ Cout,
                                                      const float* __restrict__ AX,
                                                      const _Float16* __restrict__ W16,
                                                      const float* __restrict__ Wxr,
                                                      const float* __restrict__ bfold,
                                                      float* __restrict__ cst,
                                                      float* __restrict__ h32,
                                                      _Float16* __restrict__ hTout,
                                                      int t, int last) {
    constexpr int SUBS   = (NPROD == 1) ? 2 : 1;     // 32k-subtiles per step
    constexpr int NT     = 64 / SUBS;                // K-steps
    constexpr int SUBBUF = 4096 + NPROD * 8192;      // bytes per 32k-subtile
    constexpr int BUF    = SUBS * SUBBUF;            // 24576 | 20480
    constexpr int NBUF   = (NPROD == 1) ? 4 : 6;
    constexpr int PCH    = 256 + NPROD * 512;        // chunks per subtile
    constexpr int NG     = (SUBS * PCH) / 64;        // groups/step: 24 | 20
    constexpr int GMAX   = 2;                        // groups per wave (16 waves)
    constexpr int STAGE_SZ = NBUF * BUF;             // 98304 | 122880
    // red area: inside staging bufs dead at reduction time
    constexpr int REDOFF = (NPROD == 1) ? 34816 : 86016;   // 32KB region
    // GATE layout after K-loop: ahh/ahl [0,34816) | gl0 [34816,68608)
    // | gl1 [68608,102400) | tables at 102400..105984
    constexpr int SMEMSZ = GATE ? 105984 : STAGE_SZ;
    __shared__ __align__(16) char smem[SMEMSZ];

    const int tid  = threadIdx.x;
    const int w    = tid >> 6;
    const int lane = tid & 63;
    const int ws   = w & 7;
    const int kv   = w >> 3;                // K-split half

    // XCD-aware decomposition: physical XCD = wg & 7 (round-robin dispatch).
    const int wg = blockIdx.x;
    const int x8 = wg & 7;
    const int s  = wg >> 3;                 // 0..31 slot within XCD
    const int mb = (x8 >> 1) * 8 + (s & 7);
    const int nb = (x8 & 1) * 4 + (s >> 3);
    const int m0 = mb * 64;
    const int n0 = nb * 128;

    float* wxr_s = nullptr; float* bfl_s = nullptr; float* axs = nullptr;
    if constexpr (GATE) {
        wxr_s = (float*)(smem + 102400);
        bfl_s = (float*)(smem + 103424);
        axs   = (float*)(smem + 103936);    // [bi 4][which 2][nl 64]
        const int b0c = nb * 4;
        if (tid < 64) *(float4*)&wxr_s[tid * 4] = *(const float4*)&Wxr[tid * 4];
        if (tid >= 64 && tid < 96) *(float4*)&bfl_s[(tid - 64) * 4] = *(const float4*)&bfold[(tid - 64) * 4];
        if (tid < 512)
            axs[tid] = AX[(size_t)(m0 + (tid & 63)) * XCOLS +
                          ((b0c + (tid >> 7)) * TT + t) * CIN + ((tid >> 6) & 1)];
    }

    // ---- per-wave staging groups. Group g covers chunks [g*64, g*64+64):
    // chunk cid -> subtile su = cid/PCH, r = cid%PCH.
    //   r <  256: A chunk (ko=r>>6, row=r&63), LDS off = su*SUBBUF + r*16
    //   r >= 256: B chunk r2=r-256 (plane=r2>>9, ko=(r2&511)>>7, col=r2&127),
    //             LDS off = su*SUBBUF + 4096 + r2*16
    const _Float16* gp[GMAX];
    int lbase[GMAX];
    int adv[GMAX];
    bool val[GMAX];
#pragma unroll
    for (int i = 0; i < GMAX; ++i) {
        const int g = w + 16 * i;
        val[i] = (g < NG);
        const int gg = val[i] ? g : 0;
        const int cid  = gg * 64 + lane;
        const int cid0 = gg * 64;
        const int su  = cid / PCH,  r  = cid  - su * PCH;
        const int su0 = cid0 / PCH, r0 = cid0 - su0 * PCH;
        if (r < 256) {
            gp[i]  = A2 + ((size_t)((su * 4 + (r >> 6)) * 2048) + m0 + (r & 63)) * 8;
            adv[i] = SUBS * ATILE_STRIDE;
        } else {
            const int r2 = r - 256;
            gp[i]  = B2 + (size_t)(r2 >> 9) * LOPLANE
                        + ((size_t)((su * 4 + ((r2 & 511) >> 7)) * 1024) + n0 + (r2 & 127)) * 8;
            adv[i] = SUBS * BTILE_STRIDE;
        }
        lbase[i] = su0 * SUBBUF + (r0 < 256 ? r0 * 16 : 4096 + (r0 - 256) * 16);
    }

    // ---- fragment offsets: wave (mi = ws>>2, gq = ws&3); K-part kv.
    const int lrow = lane & 31, lg = lane >> 5;
    const int mi = ws >> 2;
    const int gq = ws & 3;
    const int wc = gq * 32;
    // NPROD=1: read subtile kv of the step. NPROD=2: read plane kv.
    const int subbase = (NPROD == 1) ? kv * SUBBUF : 0;
    const int aoff0 = subbase + lg * 1024 + (mi * 32 + lrow) * 16;           // ks=0
    const int aoff1 = subbase + 2048 + lg * 1024 + (mi * 32 + lrow) * 16;    // ks=1
    const int bplane = (NPROD == 2) ? kv * 8192 : 0;
    const int boff0 = subbase + 4096 + bplane + lg * 2048 + (wc + lrow) * 16;
    const int boff1 = subbase + 4096 + bplane + 4096 + lg * 2048 + (wc + lrow) * 16;

    f32x16 acc0 = (f32x16)(0.0f), acc1 = (f32x16)(0.0f);

#define STAGE(BUFI) do {                                                       \
    char* lb = smem + (BUFI) * BUF;                                            \
    _Pragma("unroll")                                                          \
    for (int i = 0; i < GMAX; ++i) if (val[i]) {                               \
        load_lds16(gp[i], lb + lbase[i]);                                      \
        gp[i] += adv[i];                                                       \
    }                                                                          \
} while (0)

// counted vmcnt: wave-uniform predicate picks the literal (L=2 vs L=1)
#define VMW(PRED, NHI, NLO) do {                                               \
    if (PRED) asm volatile("s_waitcnt vmcnt(" #NHI ")" ::: "memory");          \
    else      asm volatile("s_waitcnt vmcnt(" #NLO ")" ::: "memory");          \
} while (0)

#define BAR() do {                                                             \
    __builtin_amdgcn_s_barrier();                                              \
    asm volatile("" ::: "memory");                                             \
} while (0)

// each wave computes ONLY its kv part: 4 ds_reads + 2 MFMAs per step
#define COMPUTE(BUFI) do {                                                     \
    const char* st = smem + (BUFI) * BUF;                                      \
    f16x8 fa0 = *(const f16x8*)(st + aoff0);                                   \
    f16x8 fa1 = *(const f16x8*)(st + aoff1);                                   \
    f16x8 fb0 = *(const f16x8*)(st + boff0);                                   \
    f16x8 fb1 = *(const f16x8*)(st + boff1);                                   \
    acc0 = __builtin_amdgcn_mfma_f32_32x32x16_f16(fa0, fb0, acc0, 0, 0, 0);    \
    acc1 = __builtin_amdgcn_mfma_f32_32x32x16_f16(fa1, fb1, acc1, 0, 0, 0);    \
} while (0)

    if constexpr (NPROD == 1) {
        // BK=64, 4 buffers, depth-2; L = (w<8)?2:1 -> steady vmcnt(4|2)
        STAGE(0);
        STAGE(1);
#pragma unroll 1
        for (int it = 0; it < NT - 2; ++it) {
            STAGE((it + 2) & 3);
            VMW(w < 8, 4, 2);
            BAR();
            COMPUTE(it & 3);
        }
        VMW(w < 8, 2, 1);
        BAR();
        COMPUTE((NT - 2) & 3);
        asm volatile("s_waitcnt vmcnt(0)" ::: "memory");
        BAR();
        COMPUTE((NT - 1) & 3);          // buf 3 @73728+
    } else {
        // BK=32, 6 buffers, depth-3; L = (w<4)?2:1 -> steady vmcnt(6|3)
        STAGE(0);
        STAGE(1);
        STAGE(2);
        int bs = 3, bc = 0;
#pragma unroll 1
        for (int it = 0; it < NT - 3; ++it) {
            STAGE(bs);
            VMW(w < 4, 6, 3);
            BAR();
            COMPUTE(bc);
            bs = (bs == 5) ? 0 : bs + 1;
            bc = (bc == 5) ? 0 : bc + 1;
        }
        VMW(w < 4, 4, 2);
        BAR();
        COMPUTE(bc); bc = (bc == 5) ? 0 : bc + 1;
        VMW(w < 4, 2, 1);
        BAR();
        COMPUTE(bc); bc = (bc == 5) ? 0 : bc + 1;
        asm volatile("s_waitcnt vmcnt(0)" ::: "memory");
        BAR();
        COMPUTE(bc);                    // bufs 1..3; red area in bufs 4-5
    }
#undef STAGE
#undef VMW
#undef BAR
#undef COMPUTE

    // ---- combine the two k-chains, then reduce across kv pair via LDS ----
    f32x16 fin;
#pragma unroll
    for (int r = 0; r < 16; ++r) fin[r] = acc0[r] + acc1[r];
    {
        float* red = (float*)(smem + REDOFF);      // [ws 8][i 16][lane 64] f32
        if (kv == 1) {
            float* rp = red + ws * 1024 + lane;
#pragma unroll
            for (int r = 0; r < 16; ++r) rp[r * 64] = fin[r];
        }
        __syncthreads();
        if (kv == 0) {
            const float* rp = red + ws * 1024 + lane;
#pragma unroll
            for (int r = 0; r < 16; ++r) fin[r] += rp[r * 64];
        }
    }

    // ---- C layout per 32x32 acc: col=lane&31, row=(r&3)+8*(r>>2)+4*lg ----
    if constexpr (!GATE) {
        if (kv == 0) {
            const int colg = n0 + wc + lrow;
#pragma unroll
            for (int r = 0; r < 16; ++r) {
                const int rp = (r & 3) + 8 * (r >> 2) + 4 * lg;
                Cout[(size_t)(m0 + mi * 32 + rp) * XCOLS + colg] = fin[r];
            }
        }
    } else {
        // -- W-frag loads (L2-resident)
        f16x8 wbh0 = *(const f16x8*)(W16 + ((size_t)(0 * 4 + gq) * 64 + lane) * 8);
        f16x8 wbh1 = *(const f16x8*)(W16 + ((size_t)(1 * 4 + gq) * 64 + lane) * 8);
        f16x8 wbl0 = *(const f16x8*)(W16 + 8192 + ((size_t)(0 * 4 + gq) * 64 + lane) * 8);
        f16x8 wbl1 = *(const f16x8*)(W16 + 8192 + ((size_t)(1 * 4 + gq) * 64 + lane) * 8);

        // -- kv0 stages Ah as hi/lo fp16 planes [64][136] at [0,34816)
        _Float16* ahh = (_Float16*)smem;
        _Float16* ahl = (_Float16*)(smem + 17408);
        if (kv == 0) {
            const int colw = wc + lrow;
#pragma unroll
            for (int r = 0; r < 16; ++r) {
                const int rp = (r & 3) + 8 * (r >> 2) + 4 * lg;
                const float v = fin[r];
                const _Float16 hi = (_Float16)v;
                ahh[(mi * 32 + rp) * 136 + colw] = hi;
                ahl[(mi * 32 + rp) * 136 + colw] = (_Float16)(v - (float)hi);
            }
        }
        __syncthreads();

        // -- gate GEMM: wave handles batches kv*2 + {0,1}
        f32x16 g0 = (f32x16)(0.0f), g1 = (f32x16)(0.0f);
#define GATEB(ACC, b) do {                                                         \
    const int arow = (mi * 32 + lrow) * 136 + (b) * 32 + lg * 8;                   \
    f16x8 fh0 = *(const f16x8*)(ahh + arow);                                       \
    f16x8 fl0 = *(const f16x8*)(ahl + arow);                                       \
    f16x8 fh1 = *(const f16x8*)(ahh + arow + 16);                                  \
    f16x8 fl1 = *(const f16x8*)(ahl + arow + 16);                                  \
    ACC = __builtin_amdgcn_mfma_f32_32x32x16_f16(fh0, wbh0, ACC, 0, 0, 0);         \
    ACC = __builtin_amdgcn_mfma_f32_32x32x16_f16(fh0, wbl0, ACC, 0, 0, 0);         \
    ACC = __builtin_amdgcn_mfma_f32_32x32x16_f16(fl0, wbh0, ACC, 0, 0, 0);         \
    ACC = __builtin_amdgcn_mfma_f32_32x32x16_f16(fh1, wbh1, ACC, 0, 0, 0);         \
    ACC = __builtin_amdgcn_mfma_f32_32x32x16_f16(fh1, wbl1, ACC, 0, 0, 0);         \
    ACC = __builtin_amdgcn_mfma_f32_32x32x16_f16(fl1, wbh1, ACC, 0, 0, 0);         \
} while (0)
        GATEB(g0, kv * 2 + 0);
        GATEB(g1, kv * 2 + 1);
#undef GATEB

        // -- pointwise: two batches concurrently (kv-split), two gl buffers
        float* glk = (float*)(smem + 34816 + kv * 33792);       // wave's buffer
        const int kvt  = tid >> 9;                              // thread's half
        const int tid2 = tid & 511;
        float* glt = (float*)(smem + 34816 + kvt * 33792);
        const int nl2 = tid2 & 63;
        const int hb  = (tid2 >> 6) * 4;
        const int b0c = nb * 4;
        const int nd  = m0 + nl2;
        const size_t ntbase = ((size_t)((nd >> 5) * 4 + ((nd >> 3) & 3)) * 1024) * 8 + (nd & 7);

#define POINTR(GACC, R) do {                                                       \
    _Pragma("unroll")                                                              \
    for (int r = 0; r < 16; ++r) {                                                 \
        const int rp = (r & 3) + 8 * (r >> 2) + 4 * lg;                            \
        glk[(mi * 32 + rp) * 132 + gq * 32 + lrow] = GACC[r];                      \
    }                                                                              \
    __syncthreads();                                                               \
    {                                                                              \
        const int bl  = kvt * 2 + (R);        /* local batch 0..3 */               \
        const float ax0 = axs[bl * 128 + nl2];                                     \
        const float ax1 = axs[bl * 128 + 64 + nl2];                                \
        const int bb = b0c + bl;                                                   \
        const size_t off = (size_t)nd * HCOLS + bb * HH + hb;                      \
        const float4 co = *(const float4*)(cst + off);                             \
        const float cold[4] = {co.x, co.y, co.z, co.w};                            \
        float cn[4], hn[4];                                                        \
        _Pragma("unroll")                                                          \
        for (int p = 0; p < 4; ++p) {                                              \
            const int hh = hb + p;                                                 \
            const float4 gt = *(const float4*)(glt + nl2 * 132 + hh * 4);          \
            const float a0 = gt.x + bfl_s[hh*4+0] + ax0*wxr_s[hh*4+0] + ax1*wxr_s[128+hh*4+0]; \
            const float a1 = gt.y + bfl_s[hh*4+1] + ax0*wxr_s[hh*4+1] + ax1*wxr_s[128+hh*4+1]; \
            const float a2 = gt.z + bfl_s[hh*4+2] + ax0*wxr_s[hh*4+2] + ax1*wxr_s[128+hh*4+2]; \
            const float a3 = gt.w + bfl_s[hh*4+3] + ax0*wxr_s[hh*4+3] + ax1*wxr_s[128+hh*4+3]; \
            const float i_ = 1.0f / (1.0f + expf(-a0));                            \
            const float f_ = 1.0f / (1.0f + expf(-a1));                            \
            const float o_ = 1.0f / (1.0f + expf(-a2));                            \
            const float g_ = tanhf(a3);                                            \
            const float ct = f_ * cold[p] + i_ * g_;                               \
            cn[p] = ct;                                                            \
            hn[p] = o_ * tanhf(ct);                                                \
        }                                                                          \
        *(float4*)(cst + off) = make_float4(cn[0], cn[1], cn[2], cn[3]);           \
        if (last) *(float4*)(h32 + off) = make_float4(hn[0], hn[1], hn[2], hn[3]); \
        _Pragma("unroll")                                                          \
        for (int p = 0; p < 4; ++p)                                                \
            hTout[ntbase + (size_t)(bb * HH + hb + p) * 8] = (_Float16)hn[p];      \
    }                                                                              \
    __syncthreads();                                                               \
} while (0)
        POINTR(g0, 0);
        POINTR(g1, 1);
#undef POINTR
    }
}

// ---------------------------------------------------------------------------
// Kernel 4: t=0 gate update only (no recurrent term), 64 nodes x 4 batches.
// ---------------------------------------------------------------------------
__global__ __launch_bounds__(256) void gate_update(const float* __restrict__ AX,
                                                   const float* __restrict__ Wxr,
                                                   const float* __restrict__ bfold,
                                                   float* __restrict__ c,
                                                   float* __restrict__ h32,
                                                   _Float16* __restrict__ hT) {
    const int n0 = blockIdx.x * 64;
    const int b0 = blockIdx.y * 4;
    const int tid = threadIdx.x;
    __shared__ float wxr[256];
    __shared__ float bfl[128];
    __shared__ float axs[2][64];

    if (tid < 64)  *(float4*)&wxr[tid * 4] = *(const float4*)&Wxr[tid * 4];
    if (tid < 32)  *(float4*)&bfl[tid * 4] = *(const float4*)&bfold[tid * 4];

    const int nl = tid & 63;
    const int hq = tid >> 6;

    const int nd = n0 + nl;
    const size_t ntbase = ((size_t)((nd >> 5) * 4 + ((nd >> 3) & 3)) * 1024) * 8 + (nd & 7);

#pragma unroll 1
    for (int bi = 0; bi < 4; ++bi) {
        const int b = b0 + bi;
        if (bi) __syncthreads();
        if (tid < 128) {
            const int which = tid >> 6, nls = tid & 63;
            axs[which][nls] = AX[(size_t)(n0 + nls) * XCOLS + (b * TT + 0) * CIN + which];
        }
        __syncthreads();

        const float ax0 = axs[0][nl], ax1 = axs[1][nl];
        float cn[8], hn[8];
#pragma unroll
        for (int u = 0; u < 8; ++u) {
            const int h = hq * 8 + u;
            float a0 = bfl[h * 4 + 0] + ax0 * wxr[h * 4 + 0] + ax1 * wxr[128 + h * 4 + 0];
            float a1 = bfl[h * 4 + 1] + ax0 * wxr[h * 4 + 1] + ax1 * wxr[128 + h * 4 + 1];
            float a2 = bfl[h * 4 + 2] + ax0 * wxr[h * 4 + 2] + ax1 * wxr[128 + h * 4 + 2];
            float a3 = bfl[h * 4 + 3] + ax0 * wxr[h * 4 + 3] + ax1 * wxr[128 + h * 4 + 3];
            const float i_ = 1.0f / (1.0f + expf(-a0));
            const float f_ = 1.0f / (1.0f + expf(-a1));
            const float o_ = 1.0f / (1.0f + expf(-a2));
            const float g_ = tanhf(a3);
            const float ct = i_ * g_;          // c_old = 0
            (void)f_;
            cn[u] = ct;
            hn[u] = o_ * tanhf(ct);
        }
        const size_t off = (size_t)nd * HCOLS + b * HH + hq * 8;
        *(float4*)(c + off)       = make_float4(cn[0], cn[1], cn[2], cn[3]);
        *(float4*)(c + off + 4)   = make_float4(cn[4], cn[5], cn[6], cn[7]);
        *(float4*)(h32 + off)     = make_float4(hn[0], hn[1], hn[2], hn[3]);
        *(float4*)(h32 + off + 4) = make_float4(hn[4], hn[5], hn[6], hn[7]);
#pragma unroll
        for (int u = 0; u < 8; ++u)
            hT[ntbase + (size_t)(b * HH + hq * 8 + u) * 8] = (_Float16)hn[u];
    }
}

// ---------------------------------------------------------------------------
// Kernel 5: out[b][th][n] = bp[th] + sum_k h[n][b*H+k] * Wp[k][th]
// ---------------------------------------------------------------------------
__global__ __launch_bounds__(256) void head_kernel(const float* __restrict__ h,
                                                   const float* __restrict__ Wp,
                                                   const float* __restrict__ bp,
                                                   float* __restrict__ out) {
    const int idx = blockIdx.x * 256 + threadIdx.x;
    const int b = idx >> 11;
    const int n = idx & (NN - 1);
    float hv[HH];
    const float* hp = h + (size_t)n * HCOLS + b * HH;
#pragma unroll
    for (int k = 0; k < HH; ++k) hv[k] = hp[k];
#pragma unroll
    for (int th = 0; th < HOR; ++th) {
        float acc = bp[th];
#pragma unroll
        for (int k = 0; k < HH; ++k) acc += hv[k] * Wp[k * HOR + th];
        out[((size_t)b * HOR + th) * NN + n] = acc;
    }
}

// ---------------------------------------------------------------------------
extern "C" void kernel_launch(void* const* d_in, const int* in_sizes, int n_in,
                              void* d_out, int out_size, void* d_ws, size_t ws_size,
                              hipStream_t stream) {
    const float* x  = (const float*)d_in[0];
    const float* E1 = (const float*)d_in[1];
    const float* E2 = (const float*)d_in[2];
    const float* Wx = (const float*)d_in[3];
    const float* bx = (const float*)d_in[4];
    const float* Wh = (const float*)d_in[5];
    const float* bh = (const float*)d_in[6];
    const float* Wp = (const float*)d_in[7];
    const float* bp = (const float*)d_in[8];

    char* ws = (char*)d_ws;
    _Float16* A2  = (_Float16*)(ws);                    //  8 MB  tiled A
    _Float16* B2x = (_Float16*)(ws + ( 8ull << 20));    //  8 MB  tiled x hi/lo
    _Float16* hT0 = (_Float16*)(ws + (16ull << 20));    //  4 MB  tiled h (ping)
    _Float16* hT1 = (_Float16*)(ws + (20ull << 20));    //  4 MB  tiled h (pong)
    float* AX   = (float*)(ws + (24ull << 20));         //  8 MB
    float* cst  = (float*)(ws + (32ull << 20));         //  8 MB
    float* h32  = (float*)(ws + (40ull << 20));         //  8 MB
    float* Wxr  = (float*)(ws + (48ull << 20) + 65536);
    float* bfold= (float*)(ws + (48ull << 20) + 131072);
    _Float16* W16 = (_Float16*)(ws + (48ull << 20) + 262144);  // 32 KB hi+lo
    float* E2T  = (float*)(ws + (48ull << 20) + 524288);       // 128 KB
    _Float16* hTb[2] = {hT0, hT1};

    e2_transpose<<<128, 256, 0, stream>>>(E2, E2T);

    // merged producers: adj rows [0,512) | x transpose [512,1536) | prep 1536
    precompute<<<512 + 1024 + 1, 256, 0, stream>>>(E1, E2T, x, Wx, bx, Wh, bh,
                                                   A2, B2x, W16, Wxr, bfold);

    // x path: AX = A*Xhi + A*Xlo, written directly (no partials)
    gemm_fused<2, 0><<<256, 1024, 0, stream>>>(A2, B2x, AX, nullptr, nullptr, nullptr,
                                               nullptr, nullptr, nullptr, nullptr, 0, 0);

    // t = 0: gates from AX only
    gate_update<<<dim3(NN / 64, BB / 4), 256, 0, stream>>>(AX, Wxr, bfold,
                                                           cst, h32, hTb[0]);
    // t = 1..15: fused GEMM + MFMA gate epilogue; hT ping-pong
    for (int t = 1; t < TT; ++t) {
        gemm_fused<1, 1><<<256, 1024, 0, stream>>>(A2, hTb[(t + 1) & 1], nullptr, AX,
                                                   W16, Wxr, bfold, cst, h32,
                                                   hTb[t & 1], t, t == TT - 1 ? 1 : 0);
    }

    head_kernel<<<(BB * NN) / 256, 256, 0, stream>>>(h32, Wp, bp, (float*)d_out);
}

// Round 16
// 528.869 us; speedup vs baseline: 1.0090x; 1.0090x over previous
//
#include <hip/hip_runtime.h>
#include <hip/hip_bf16.h>
#include <cstddef>
#include <cstdint>

#define NN 2048      // nodes (M and K of the big GEMMs)
#define CIN 2
#define HH 32        // hidden
#define EMB 16
#define HOR 12
#define BB 32        // batch
#define TT 16        // time steps
#define GC 128       // 4*HH gate channels
#define XCOLS 1024   // B*T*C
#define HCOLS 1024   // B*H  (GEMM N dim)

// Tiled fp16 operand layouts (32-k tiles, 8-elem chunks):
//   A2t [tt=64][ko=4][row=2048][e=8] : elem ((tt*4+ko)*2048+row)*8+e = A[row][tt*32+ko*8+e]
//   hTt [tt=64][ko=4][col=1024][e=8] : elem ((tt*4+ko)*1024+col)*8+e = h[node=tt*32+ko*8+e][col]
//   B2xt: hi plane same shape as hTt; lo plane at +LOPLANE elements.
#define ATILE_STRIDE 65536   // 4*2048*8 elements per 32-k tile of A
#define BTILE_STRIDE 32768   // 4*1024*8 elements per 32-k tile of B
#define LOPLANE 2097152      // elements per x plane (64*4*1024*8)

typedef __attribute__((ext_vector_type(8))) _Float16 f16x8;
typedef __attribute__((ext_vector_type(16))) float f32x16;

__device__ __forceinline__ void load_lds16(const void* g, void* l) {
    __builtin_amdgcn_global_load_lds(
        (const __attribute__((address_space(1))) void*)g,
        (__attribute__((address_space(3))) void*)l, 16, 0, 0);
}

// ---------------------------------------------------------------------------
// Kernel 0: E2T[k][j] = E2[j][k]  (128 KB; enables coalesced softmax loads)
// ---------------------------------------------------------------------------
__global__ __launch_bounds__(256) void e2_transpose(const float* __restrict__ E2,
                                                    float* __restrict__ E2T) {
    const int idx = blockIdx.x * 256 + threadIdx.x;   // 32768 elements
    const int k = idx >> 11;
    const int j = idx & 2047;
    E2T[idx] = E2[j * EMB + k];     // write coalesced; read strided (tiny)
}

// ---------------------------------------------------------------------------
// Kernel 1 (merged): blocks [0,512): adjacency softmax, wave-per-row with
// lane-coalesced E2T loads + shfl reductions. Blocks [512,1536): x -> B2xt
// hi/lo (one f16x8 store per plane). Block 1536: weight prep.
// ---------------------------------------------------------------------------
__global__ __launch_bounds__(256) void precompute(const float* __restrict__ E1,
                                                  const float* __restrict__ E2T,
                                                  const float* __restrict__ x,
                                                  const float* __restrict__ Wx,
                                                  const float* __restrict__ bx,
                                                  const float* __restrict__ Wh,
                                                  const float* __restrict__ bh,
                                                  _Float16* __restrict__ A2,
                                                  _Float16* __restrict__ B2x,
                                                  _Float16* __restrict__ W16,
                                                  float* __restrict__ Wxr,
                                                  float* __restrict__ bfold) {
    const int blk = blockIdx.x;
    const int tid = threadIdx.x;

    if (blk < 512) {
        // ---- adjacency softmax: row i, lane l owns j = c*64 + l
        const int i = blk * 4 + (tid >> 6);
        const int l = tid & 63;
        float e1[EMB];
#pragma unroll
        for (int k = 0; k < EMB; ++k) e1[k] = E1[i * EMB + k];   // uniform

        float s[32];
#pragma unroll
        for (int c = 0; c < 32; ++c) s[c] = 0.f;
#pragma unroll
        for (int k = 0; k < EMB; ++k) {
            const float ek = e1[k];
            const float* p = E2T + k * 2048 + l;
#pragma unroll
            for (int c = 0; c < 32; ++c) s[c] = fmaf(ek, p[c * 64], s[c]);
        }
        float mx = 0.f;                         // relu floor
#pragma unroll
        for (int c = 0; c < 32; ++c) { s[c] = fmaxf(s[c], 0.f); mx = fmaxf(mx, s[c]); }
#pragma unroll
        for (int off = 32; off > 0; off >>= 1) mx = fmaxf(mx, __shfl_xor(mx, off, 64));
        float sum = 0.f;
#pragma unroll
        for (int c = 0; c < 32; ++c) { s[c] = expf(s[c] - mx); sum += s[c]; }
#pragma unroll
        for (int off = 32; off > 0; off >>= 1) sum += __shfl_xor(sum, off, 64);
        const float inv = 1.0f / sum;
        // store: j = c*64+l -> chunk (j>>3) = c*8 + (l>>3), elem j&7 = l&7
        const int chb = (l >> 3);
        const int e   = l & 7;
#pragma unroll
        for (int c = 0; c < 32; ++c)
            A2[((size_t)(c * 8 + chb) * 2048 + i) * 8 + e] = (_Float16)(s[c] * inv);
    } else if (blk < 512 + 1024) {
        // ---- x transpose: idx -> (jc, col); thread owns 8 contiguous nodes
        const int idx = (blk - 512) * 256 + tid;
        const int col = idx & 1023;              // (b*T+t)*C + c
        const int jc  = idx >> 10;               // node chunk 0..255
        const int bt  = col >> 1;
        const int c   = col & 1;
        const float* xp = x + ((size_t)bt * NN + jc * 8) * CIN + c;
        f16x8 vh, vl;
#pragma unroll
        for (int e = 0; e < 8; ++e) {
            const float v = xp[e * CIN];
            const _Float16 hi = (_Float16)v;
            vh[e] = hi;
            vl[e] = (_Float16)(v - (float)hi);
        }
        const size_t base = ((size_t)jc * 1024 + col) * 8;
        *(f16x8*)(B2x + base) = vh;
        *(f16x8*)(B2x + base + LOPLANE) = vl;
    } else {
        // ---- weight prep (single block)
#pragma unroll
        for (int r = 0; r < 32; ++r) {
            const int idx = r * 256 + tid;      // 8192 frag entries
            const int e  = idx & 7;
            const int ln = (idx >> 3) & 63;
            const int gq = (idx >> 9) & 3;
            const int kh = (idx >> 11) & 1;
            const int k  = kh * 16 + (ln >> 5) * 8 + e;
            const int ch = gq * 32 + (ln & 31); // channel = h*4 + gate
            const float v = Wh[k * GC + (ch & 3) * HH + (ch >> 2)];
            const _Float16 hi = (_Float16)v;
            W16[idx] = hi;
            W16[8192 + idx] = (_Float16)(v - (float)hi);
        }
        {
            const int idx = tid;                // 256
            const int c = idx >> 7, rem = idx & 127;
            const int h = rem >> 2, g = rem & 3;
            Wxr[idx] = Wx[c * GC + g * HH + h];
        }
        if (tid < 128) {
            const int h = tid >> 2, g = tid & 3;
            bfold[tid] = bx[g * HH + h] + bh[g * HH + h];
        }
    }
}

// ---------------------------------------------------------------------------
// Kernel 3: fused full-K fp16 MFMA GEMM (32x32x16) + MFMA gate epilogue.
// Tile M=64 x N=128, K=2048. Grid 256, 1 block/CU, 512 threads = 8 waves.
// ROUND 16 recurrent K-loop (NPROD=1): B-DEDUP wave roles. Wave (gqk = w&3,
// kvk = w>>2); each wave computes BOTH mi tiles of column quadrant gqk for
// its kv subtile (4 acc chains), reading A 4 frags + B 2 frags = 6KB per
// step for 4 MFMAs. Per-subtile fragment reads drop 32KB -> 24KB (-25%,
// B-duplication across mi-waves eliminated) at identical DMA/MFMA/barrier
// structure (round-10 shell verbatim: BK=64, 4 bufs, depth-2, uniform 3
// DMA-groups/wave -> branchless vmcnt(6)). kv pair summed at the end via a
// 32KB LDS exchange in buffers 0-1 (dead: last two COMPUTEs read bufs 2,3).
// NPROD=2 (x path): round-13 shell verbatim (BK=32, 6 bufs, VMW(9,6)).
// GATE epilogue (round 13, unchanged): roles re-derived (mi=w>>2, gq=w&3)
// after the ah-plane barrier; hi/lo-split MFMA gate GEMM + LSTM pointwise.
// XCD swizzle: XCD owns 8 mb x 4 nb -> 2MB A-slab + 2MB hT-cols in L2.
// ---------------------------------------------------------------------------
template <int NPROD, int GATE>
__global__ __launch_bounds__(512, 2) void gemm_fused(const _Float16* __restrict__ A2,
                                                     const _Float16* __restrict__ B2,
                                                     float* __restrict__ Cout,
                                                     const float* __restrict__ AX,
                                                     const _Float16* __restrict__ W16,
                                                     const float* __restrict__ Wxr,
                                                     const float* __restrict__ bfold,
                                                     float* __restrict__ cst,
                                                     float* __restrict__ h32,
                                                     _Float16* __restrict__ hTout,
                                                     int t, int last) {
    constexpr int SUBS   = (NPROD == 1) ? 2 : 1;     // 32k-subtiles per step
    constexpr int NT     = 64 / SUBS;                // K-steps
    constexpr int SUBBUF = 4096 + NPROD * 8192;      // bytes per 32k-subtile
    constexpr int BUF    = SUBS * SUBBUF;            // 24576 | 20480
    constexpr int NBUF   = (NPROD == 1) ? 4 : 6;
    constexpr int PCH    = 256 + NPROD * 512;        // chunks per subtile
    constexpr int NG     = (SUBS * PCH) / 64;        // groups/step: 24 | 20
    constexpr int GMAX   = 3;                        // groups per wave
    constexpr int STAGE_SZ = NBUF * BUF;             // 98304 | 122880
    constexpr int SMEMSZ = GATE ? (STAGE_SZ + 1024 + 512 + 2048) : STAGE_SZ;
    __shared__ __align__(16) char smem[SMEMSZ];

    const int tid  = threadIdx.x;
    const int w    = tid >> 6;
    const int lane = tid & 63;

    // XCD-aware decomposition: physical XCD = wg & 7 (round-robin dispatch).
    const int wg = blockIdx.x;
    const int x8 = wg & 7;
    const int s  = wg >> 3;                 // 0..31 slot within XCD
    const int mb = (x8 >> 1) * 8 + (s & 7);
    const int nb = (x8 & 1) * 4 + (s >> 3);
    const int m0 = mb * 64;
    const int n0 = nb * 128;

    float* wxr_s = nullptr; float* bfl_s = nullptr; float* axs = nullptr;
    if constexpr (GATE) {
        wxr_s = (float*)(smem + STAGE_SZ);
        bfl_s = (float*)(smem + STAGE_SZ + 1024);
        axs   = (float*)(smem + STAGE_SZ + 1536);   // [bi 4][which 2][nl 64]
        const int b0c = nb * 4;
        if (tid < 64) *(float4*)&wxr_s[tid * 4] = *(const float4*)&Wxr[tid * 4];
        if (tid < 32) *(float4*)&bfl_s[tid * 4] = *(const float4*)&bfold[tid * 4];
        axs[tid] = AX[(size_t)(m0 + (tid & 63)) * XCOLS +
                      ((b0c + (tid >> 7)) * TT + t) * CIN + ((tid >> 6) & 1)];
    }

    // ---- per-wave staging groups. Group g covers chunks [g*64, g*64+64):
    // chunk cid -> subtile su = cid/PCH, r = cid%PCH.
    //   r <  256: A chunk (ko=r>>6, row=r&63), LDS off = su*SUBBUF + r*16
    //   r >= 256: B chunk r2=r-256 (plane=r2>>9, ko=(r2&511)>>7, col=r2&127),
    //             LDS off = su*SUBBUF + 4096 + r2*16
    const _Float16* gp[GMAX];
    int lbase[GMAX];
    int adv[GMAX];
    bool val[GMAX];
#pragma unroll
    for (int i = 0; i < GMAX; ++i) {
        const int g = w + 8 * i;
        val[i] = (g < NG);
        const int gg = val[i] ? g : 0;
        const int cid  = gg * 64 + lane;
        const int cid0 = gg * 64;
        const int su  = cid / PCH,  r  = cid  - su * PCH;
        const int su0 = cid0 / PCH, r0 = cid0 - su0 * PCH;
        if (r < 256) {
            gp[i]  = A2 + ((size_t)((su * 4 + (r >> 6)) * 2048) + m0 + (r & 63)) * 8;
            adv[i] = SUBS * ATILE_STRIDE;
        } else {
            const int r2 = r - 256;
            gp[i]  = B2 + (size_t)(r2 >> 9) * LOPLANE
                        + ((size_t)((su * 4 + ((r2 & 511) >> 7)) * 1024) + n0 + (r2 & 127)) * 8;
            adv[i] = SUBS * BTILE_STRIDE;
        }
        lbase[i] = su0 * SUBBUF + (r0 < 256 ? r0 * 16 : 4096 + (r0 - 256) * 16);
    }

    // ---- roles & fragment offsets ----
    const int lrow = lane & 31, lg = lane >> 5;
    const int mi = w >> 2;          // epilogue / NPROD==2 role
    const int gq = w & 3;           // epilogue / NPROD==2 role
    const int wc = gq * 32;
    // NPROD==2 offsets (round-13):
    const int aoff0 = lg * 1024 + (mi * 32 + lrow) * 16;           // ks=0
    const int aoff1 = 2048 + lg * 1024 + (mi * 32 + lrow) * 16;    // ks=1
    const int boff0 = 4096 + lg * 2048 + (wc + lrow) * 16;
    const int boff1 = 4096 + 4096 + lg * 2048 + (wc + lrow) * 16;
    // NPROD==1 offsets: wave (gqk = w&3) covers both mi; kv subtile kvk.
    const int gqk = w & 3;
    const int kvk = w >> 2;
    const int subb  = kvk * SUBBUF;
    const int a00 = subb + lg * 1024 + lrow * 16;            // mi=0 ks=0
    const int a01 = subb + 2048 + lg * 1024 + lrow * 16;     // mi=0 ks=1
    const int a10 = a00 + 512;                               // mi=1 ks=0
    const int a11 = a01 + 512;                               // mi=1 ks=1
    const int bk0 = subb + 4096 + lg * 2048 + (gqk * 32 + lrow) * 16;  // ks=0
    const int bk1 = bk0 + 4096;                                        // ks=1

    f32x16 acc0 = (f32x16)(0.0f), acc1 = (f32x16)(0.0f);   // shared / mi0
    f32x16 acc2 = (f32x16)(0.0f), acc3 = (f32x16)(0.0f);   // mi1 (NPROD==1)

#define STAGE(BUFI) do {                                                       \
    char* lb = smem + (BUFI) * BUF;                                            \
    _Pragma("unroll")                                                          \
    for (int i = 0; i < GMAX; ++i) if (val[i]) {                               \
        load_lds16(gp[i], lb + lbase[i]);                                      \
        gp[i] += adv[i];                                                       \
    }                                                                          \
} while (0)

#define VMW(NHI, NLO) do {                                                     \
    if (w < 4) asm volatile("s_waitcnt vmcnt(" #NHI ")" ::: "memory");         \
    else       asm volatile("s_waitcnt vmcnt(" #NLO ")" ::: "memory");         \
} while (0)

#define BAR() do {                                                             \
    __builtin_amdgcn_s_barrier();                                              \
    asm volatile("" ::: "memory");                                             \
} while (0)

// NPROD==1: wave computes both mi tiles of its kv subtile (6 reads, 4 MFMAs)
#define COMPUTE1(BUFI) do {                                                    \
    const char* st = smem + (BUFI) * BUF;                                      \
    f16x8 fa00 = *(const f16x8*)(st + a00);                                    \
    f16x8 fa01 = *(const f16x8*)(st + a01);                                    \
    f16x8 fa10 = *(const f16x8*)(st + a10);                                    \
    f16x8 fa11 = *(const f16x8*)(st + a11);                                    \
    f16x8 fb0  = *(const f16x8*)(st + bk0);                                    \
    f16x8 fb1  = *(const f16x8*)(st + bk1);                                    \
    acc0 = __builtin_amdgcn_mfma_f32_32x32x16_f16(fa00, fb0, acc0, 0, 0, 0);   \
    acc1 = __builtin_amdgcn_mfma_f32_32x32x16_f16(fa01, fb1, acc1, 0, 0, 0);   \
    acc2 = __builtin_amdgcn_mfma_f32_32x32x16_f16(fa10, fb0, acc2, 0, 0, 0);   \
    acc3 = __builtin_amdgcn_mfma_f32_32x32x16_f16(fa11, fb1, acc3, 0, 0, 0);   \
} while (0)

// NPROD==2: round-13 compute (hi+lo planes into acc0/acc1)
#define COMPUTE2(BUFI) do {                                                    \
    const char* st = smem + (BUFI) * BUF;                                      \
    f16x8 fa0 = *(const f16x8*)(st + aoff0);                                   \
    f16x8 fa1 = *(const f16x8*)(st + aoff1);                                   \
    f16x8 fb0 = *(const f16x8*)(st + boff0);                                   \
    f16x8 fb1 = *(const f16x8*)(st + boff1);                                   \
    acc0 = __builtin_amdgcn_mfma_f32_32x32x16_f16(fa0, fb0, acc0, 0, 0, 0);    \
    acc1 = __builtin_amdgcn_mfma_f32_32x32x16_f16(fa1, fb1, acc1, 0, 0, 0);    \
    f16x8 fc0 = *(const f16x8*)(st + boff0 + 8192);                            \
    f16x8 fc1 = *(const f16x8*)(st + boff1 + 8192);                            \
    acc0 = __builtin_amdgcn_mfma_f32_32x32x16_f16(fa0, fc0, acc0, 0, 0, 0);    \
    acc1 = __builtin_amdgcn_mfma_f32_32x32x16_f16(fa1, fc1, acc1, 0, 0, 0);    \
} while (0)

    if constexpr (NPROD == 1) {
        // BK=64, 4 buffers, depth-2; NG=24 -> uniform 3 loads/wave -> vmcnt(6)
        STAGE(0);
        STAGE(1);
#pragma unroll 1
        for (int it = 0; it < NT - 2; ++it) {
            STAGE((it + 2) & 3);
            asm volatile("s_waitcnt vmcnt(6)" ::: "memory");
            BAR();
            COMPUTE1(it & 3);
        }
        asm volatile("s_waitcnt vmcnt(3)" ::: "memory");
        BAR();
        COMPUTE1((NT - 2) & 3);          // buf 2
        asm volatile("s_waitcnt vmcnt(0)" ::: "memory");
        BAR();
        COMPUTE1((NT - 1) & 3);          // buf 3; bufs 0-1 now dead
    } else {
        // BK=32, 6 buffers, depth-3 (round-13 verbatim)
        STAGE(0);
        STAGE(1);
        STAGE(2);
        int bs = 3, bc = 0;
#pragma unroll 1
        for (int it = 0; it < NT - 3; ++it) {
            STAGE(bs);
            VMW(9, 6);
            BAR();
            COMPUTE2(bc);
            bs = (bs == 5) ? 0 : bs + 1;
            bc = (bc == 5) ? 0 : bc + 1;
        }
        VMW(6, 4);
        BAR();
        COMPUTE2(bc); bc = (bc == 5) ? 0 : bc + 1;
        VMW(3, 2);
        BAR();
        COMPUTE2(bc); bc = (bc == 5) ? 0 : bc + 1;
        asm volatile("s_waitcnt vmcnt(0)" ::: "memory");
        BAR();
        COMPUTE2(bc);
    }
#undef STAGE
#undef VMW
#undef BAR
#undef COMPUTE1
#undef COMPUTE2

    if constexpr (NPROD == 1) {
        // ---- combine ks chains; reduce kv pair via LDS (bufs 0-1, dead) ----
        f32x16 fin0, fin1;
#pragma unroll
        for (int r = 0; r < 16; ++r) { fin0[r] = acc0[r] + acc1[r]; fin1[r] = acc2[r] + acc3[r]; }
        {
            float* red = (float*)smem;            // [tile 8][r 16][lane 64]
            if (kvk == 1) {
                float* rp0 = red + (gqk * 2 + 0) * 1024 + lane;
                float* rp1 = red + (gqk * 2 + 1) * 1024 + lane;
#pragma unroll
                for (int r = 0; r < 16; ++r) { rp0[r * 64] = fin0[r]; rp1[r * 64] = fin1[r]; }
            }
            __syncthreads();
            if (kvk == 0) {
                const float* rp0 = red + (gqk * 2 + 0) * 1024 + lane;
                const float* rp1 = red + (gqk * 2 + 1) * 1024 + lane;
#pragma unroll
                for (int r = 0; r < 16; ++r) { fin0[r] += rp0[r * 64]; fin1[r] += rp1[r * 64]; }
            }
            __syncthreads();                      // red reads done before reuse
        }

        if constexpr (!GATE) {
            if (kvk == 0) {
                const int colg = n0 + gqk * 32 + lrow;
#pragma unroll
                for (int r = 0; r < 16; ++r) {
                    const int rp = (r & 3) + 8 * (r >> 2) + 4 * lg;
                    Cout[(size_t)(m0 + rp) * XCOLS + colg]      = fin0[r];
                    Cout[(size_t)(m0 + 32 + rp) * XCOLS + colg] = fin1[r];
                }
            }
        } else {
            // -- W-frag loads (L2-resident)
            f16x8 wbh0 = *(const f16x8*)(W16 + ((size_t)(0 * 4 + gq) * 64 + lane) * 8);
            f16x8 wbh1 = *(const f16x8*)(W16 + ((size_t)(1 * 4 + gq) * 64 + lane) * 8);
            f16x8 wbl0 = *(const f16x8*)(W16 + 8192 + ((size_t)(0 * 4 + gq) * 64 + lane) * 8);
            f16x8 wbl1 = *(const f16x8*)(W16 + 8192 + ((size_t)(1 * 4 + gq) * 64 + lane) * 8);

            // -- kv0 waves stage Ah (both mi tiles) as hi/lo fp16 [64][136]
            _Float16* ahh = (_Float16*)smem;
            _Float16* ahl = (_Float16*)(smem + 17408);
            if (kvk == 0) {
                const int colw = gqk * 32 + lrow;
#pragma unroll
                for (int r = 0; r < 16; ++r) {
                    const int rp = (r & 3) + 8 * (r >> 2) + 4 * lg;
                    const float v0 = fin0[r];
                    const _Float16 h0 = (_Float16)v0;
                    ahh[rp * 136 + colw] = h0;
                    ahl[rp * 136 + colw] = (_Float16)(v0 - (float)h0);
                    const float v1 = fin1[r];
                    const _Float16 h1 = (_Float16)v1;
                    ahh[(32 + rp) * 136 + colw] = h1;
                    ahl[(32 + rp) * 136 + colw] = (_Float16)(v1 - (float)h1);
                }
            }
            __syncthreads();

            // -- gate GEMM (round-13 roles mi,gq): [32n x 32ch] per batch
            f32x16 g0 = (f32x16)(0.0f), g1 = (f32x16)(0.0f);
            f32x16 g2 = (f32x16)(0.0f), g3 = (f32x16)(0.0f);
#define GATEB(ACC, b) do {                                                         \
    const int arow = (mi * 32 + lrow) * 136 + (b) * 32 + lg * 8;                   \
    f16x8 fh0 = *(const f16x8*)(ahh + arow);                                       \
    f16x8 fl0 = *(const f16x8*)(ahl + arow);                                       \
    f16x8 fh1 = *(const f16x8*)(ahh + arow + 16);                                  \
    f16x8 fl1 = *(const f16x8*)(ahl + arow + 16);                                  \
    ACC = __builtin_amdgcn_mfma_f32_32x32x16_f16(fh0, wbh0, ACC, 0, 0, 0);         \
    ACC = __builtin_amdgcn_mfma_f32_32x32x16_f16(fh0, wbl0, ACC, 0, 0, 0);         \
    ACC = __builtin_amdgcn_mfma_f32_32x32x16_f16(fl0, wbh0, ACC, 0, 0, 0);         \
    ACC = __builtin_amdgcn_mfma_f32_32x32x16_f16(fh1, wbh1, ACC, 0, 0, 0);         \
    ACC = __builtin_amdgcn_mfma_f32_32x32x16_f16(fh1, wbl1, ACC, 0, 0, 0);         \
    ACC = __builtin_amdgcn_mfma_f32_32x32x16_f16(fl1, wbh1, ACC, 0, 0, 0);         \
} while (0)
            GATEB(g0, 0); GATEB(g1, 1); GATEB(g2, 2); GATEB(g3, 3);
#undef GATEB

            // -- per-b: stage gate tile to LDS f32 [64][132]; pointwise LSTM
            float* gl = (float*)(smem + 34816);
            const int nl2 = tid & 63;
            const int hb  = (tid >> 6) * 4;
            const int b0c = nb * 4;
            const int nd  = m0 + nl2;
            const size_t ntbase = ((size_t)((nd >> 5) * 4 + ((nd >> 3) & 3)) * 1024) * 8 + (nd & 7);

#define POINT(ACC, bi) do {                                                        \
    _Pragma("unroll")                                                              \
    for (int r = 0; r < 16; ++r) {                                                 \
        const int rp = (r & 3) + 8 * (r >> 2) + 4 * lg;                            \
        gl[(mi * 32 + rp) * 132 + gq * 32 + lrow] = ACC[r];                        \
    }                                                                              \
    __syncthreads();                                                               \
    {                                                                              \
        const float ax0 = axs[(bi) * 128 + nl2];                                   \
        const float ax1 = axs[(bi) * 128 + 64 + nl2];                              \
        const int bb = b0c + (bi);                                                 \
        const size_t off = (size_t)nd * HCOLS + bb * HH + hb;                      \
        const float4 co = *(const float4*)(cst + off);                             \
        const float cold[4] = {co.x, co.y, co.z, co.w};                            \
        float cn[4], hn[4];                                                        \
        _Pragma("unroll")                                                          \
        for (int p = 0; p < 4; ++p) {                                              \
            const int hh = hb + p;                                                 \
            const float4 gt = *(const float4*)(gl + nl2 * 132 + hh * 4);           \
            const float a0 = gt.x + bfl_s[hh*4+0] + ax0*wxr_s[hh*4+0] + ax1*wxr_s[128+hh*4+0]; \
            const float a1 = gt.y + bfl_s[hh*4+1] + ax0*wxr_s[hh*4+1] + ax1*wxr_s[128+hh*4+1]; \
            const float a2 = gt.z + bfl_s[hh*4+2] + ax0*wxr_s[hh*4+2] + ax1*wxr_s[128+hh*4+2]; \
            const float a3 = gt.w + bfl_s[hh*4+3] + ax0*wxr_s[hh*4+3] + ax1*wxr_s[128+hh*4+3]; \
            const float i_ = 1.0f / (1.0f + expf(-a0));                            \
            const float f_ = 1.0f / (1.0f + expf(-a1));                            \
            const float o_ = 1.0f / (1.0f + expf(-a2));                            \
            const float g_ = tanhf(a3);                                            \
            const float ct = f_ * cold[p] + i_ * g_;                               \
            cn[p] = ct;                                                            \
            hn[p] = o_ * tanhf(ct);                                                \
        }                                                                          \
        *(float4*)(cst + off) = make_float4(cn[0], cn[1], cn[2], cn[3]);           \
        if (last) *(float4*)(h32 + off) = make_float4(hn[0], hn[1], hn[2], hn[3]); \
        _Pragma("unroll")                                                          \
        for (int p = 0; p < 4; ++p)                                                \
            hTout[ntbase + (size_t)(bb * HH + hb + p) * 8] = (_Float16)hn[p];      \
    }                                                                              \
    __syncthreads();                                                               \
} while (0)
            POINT(g0, 0); POINT(g1, 1); POINT(g2, 2); POINT(g3, 3);
#undef POINT
        }
    } else {
        // NPROD==2: C store (round-13)
        const int colg = n0 + wc + lrow;
#pragma unroll
        for (int r = 0; r < 16; ++r) {
            const int rp = (r & 3) + 8 * (r >> 2) + 4 * lg;
            Cout[(size_t)(m0 + mi * 32 + rp) * XCOLS + colg] = acc0[r] + acc1[r];
        }
    }
}

// ---------------------------------------------------------------------------
// Kernel 4: t=0 gate update only (no recurrent term), 64 nodes x 4 batches.
// ---------------------------------------------------------------------------
__global__ __launch_bounds__(256) void gate_update(const float* __restrict__ AX,
                                                   const float* __restrict__ Wxr,
                                                   const float* __restrict__ bfold,
                                                   float* __restrict__ c,
                                                   float* __restrict__ h32,
                                                   _Float16* __restrict__ hT) {
    const int n0 = blockIdx.x * 64;
    const int b0 = blockIdx.y * 4;
    const int tid = threadIdx.x;
    __shared__ float wxr[256];
    __shared__ float bfl[128];
    __shared__ float axs[2][64];

    if (tid < 64)  *(float4*)&wxr[tid * 4] = *(const float4*)&Wxr[tid * 4];
    if (tid < 32)  *(float4*)&bfl[tid * 4] = *(const float4*)&bfold[tid * 4];

    const int nl = tid & 63;
    const int hq = tid >> 6;

    const int nd = n0 + nl;
    const size_t ntbase = ((size_t)((nd >> 5) * 4 + ((nd >> 3) & 3)) * 1024) * 8 + (nd & 7);

#pragma unroll 1
    for (int bi = 0; bi < 4; ++bi) {
        const int b = b0 + bi;
        if (bi) __syncthreads();
        if (tid < 128) {
            const int which = tid >> 6, nls = tid & 63;
            axs[which][nls] = AX[(size_t)(n0 + nls) * XCOLS + (b * TT + 0) * CIN + which];
        }
        __syncthreads();

        const float ax0 = axs[0][nl], ax1 = axs[1][nl];
        float cn[8], hn[8];
#pragma unroll
        for (int u = 0; u < 8; ++u) {
            const int h = hq * 8 + u;
            float a0 = bfl[h * 4 + 0] + ax0 * wxr[h * 4 + 0] + ax1 * wxr[128 + h * 4 + 0];
            float a1 = bfl[h * 4 + 1] + ax0 * wxr[h * 4 + 1] + ax1 * wxr[128 + h * 4 + 1];
            float a2 = bfl[h * 4 + 2] + ax0 * wxr[h * 4 + 2] + ax1 * wxr[128 + h * 4 + 2];
            float a3 = bfl[h * 4 + 3] + ax0 * wxr[h * 4 + 3] + ax1 * wxr[128 + h * 4 + 3];
            const float i_ = 1.0f / (1.0f + expf(-a0));
            const float f_ = 1.0f / (1.0f + expf(-a1));
            const float o_ = 1.0f / (1.0f + expf(-a2));
            const float g_ = tanhf(a3);
            const float ct = i_ * g_;          // c_old = 0
            (void)f_;
            cn[u] = ct;
            hn[u] = o_ * tanhf(ct);
        }
        const size_t off = (size_t)nd * HCOLS + b * HH + hq * 8;
        *(float4*)(c + off)       = make_float4(cn[0], cn[1], cn[2], cn[3]);
        *(float4*)(c + off + 4)   = make_float4(cn[4], cn[5], cn[6], cn[7]);
        *(float4*)(h32 + off)     = make_float4(hn[0], hn[1], hn[2], hn[3]);
        *(float4*)(h32 + off + 4) = make_float4(hn[4], hn[5], hn[6], hn[7]);
#pragma unroll
        for (int u = 0; u < 8; ++u)
            hT[ntbase + (size_t)(b * HH + hq * 8 + u) * 8] = (_Float16)hn[u];
    }
}

// ---------------------------------------------------------------------------
// Kernel 5: out[b][th][n] = bp[th] + sum_k h[n][b*H+k] * Wp[k][th]
// ---------------------------------------------------------------------------
__global__ __launch_bounds__(256) void head_kernel(const float* __restrict__ h,
                                                   const float* __restrict__ Wp,
                                                   const float* __restrict__ bp,
                                                   float* __restrict__ out) {
    const int idx = blockIdx.x * 256 + threadIdx.x;
    const int b = idx >> 11;
    const int n = idx & (NN - 1);
    float hv[HH];
    const float* hp = h + (size_t)n * HCOLS + b * HH;
#pragma unroll
    for (int k = 0; k < HH; ++k) hv[k] = hp[k];
#pragma unroll
    for (int th = 0; th < HOR; ++th) {
        float acc = bp[th];
#pragma unroll
        for (int k = 0; k < HH; ++k) acc += hv[k] * Wp[k * HOR + th];
        out[((size_t)b * HOR + th) * NN + n] = acc;
    }
}

// ---------------------------------------------------------------------------
extern "C" void kernel_launch(void* const* d_in, const int* in_sizes, int n_in,
                              void* d_out, int out_size, void* d_ws, size_t ws_size,
                              hipStream_t stream) {
    const float* x  = (const float*)d_in[0];
    const float* E1 = (const float*)d_in[1];
    const float* E2 = (const float*)d_in[2];
    const float* Wx = (const float*)d_in[3];
    const float* bx = (const float*)d_in[4];
    const float* Wh = (const float*)d_in[5];
    const float* bh = (const float*)d_in[6];
    const float* Wp = (const float*)d_in[7];
    const float* bp = (const float*)d_in[8];

    char* ws = (char*)d_ws;
    _Float16* A2  = (_Float16*)(ws);                    //  8 MB  tiled A
    _Float16* B2x = (_Float16*)(ws + ( 8ull << 20));    //  8 MB  tiled x hi/lo
    _Float16* hT0 = (_Float16*)(ws + (16ull << 20));    //  4 MB  tiled h (ping)
    _Float16* hT1 = (_Float16*)(ws + (20ull << 20));    //  4 MB  tiled h (pong)
    float* AX   = (float*)(ws + (24ull << 20));         //  8 MB
    float* cst  = (float*)(ws + (32ull << 20));         //  8 MB
    float* h32  = (float*)(ws + (40ull << 20));         //  8 MB
    float* Wxr  = (float*)(ws + (48ull << 20) + 65536);
    float* bfold= (float*)(ws + (48ull << 20) + 131072);
    _Float16* W16 = (_Float16*)(ws + (48ull << 20) + 262144);  // 32 KB hi+lo
    float* E2T  = (float*)(ws + (48ull << 20) + 524288);       // 128 KB
    _Float16* hTb[2] = {hT0, hT1};

    e2_transpose<<<128, 256, 0, stream>>>(E2, E2T);

    // merged producers: adj rows [0,512) | x transpose [512,1536) | prep 1536
    precompute<<<512 + 1024 + 1, 256, 0, stream>>>(E1, E2T, x, Wx, bx, Wh, bh,
                                                   A2, B2x, W16, Wxr, bfold);

    // x path: AX = A*Xhi + A*Xlo, written directly (no partials)
    gemm_fused<2, 0><<<256, 512, 0, stream>>>(A2, B2x, AX, nullptr, nullptr, nullptr,
                                              nullptr, nullptr, nullptr, nullptr, 0, 0);

    // t = 0: gates from AX only
    gate_update<<<dim3(NN / 64, BB / 4), 256, 0, stream>>>(AX, Wxr, bfold,
                                                           cst, h32, hTb[0]);
    // t = 1..15: fused GEMM + MFMA gate epilogue; hT ping-pong
    for (int t = 1; t < TT; ++t) {
        gemm_fused<1, 1><<<256, 512, 0, stream>>>(A2, hTb[(t + 1) & 1], nullptr, AX,
                                                  W16, Wxr, bfold, cst, h32,
                                                  hTb[t & 1], t, t == TT - 1 ? 1 : 0);
    }

    head_kernel<<<(BB * NN) / 256, 256, 0, stream>>>(h32, Wp, bp, (float*)d_out);
}